// Round 2
// baseline (241.326 us; speedup 1.0000x reference)
//
#include <hip/hip_runtime.h>
#include <math.h>

#define BATCH 64
#define CC    256
#define ATTRN 300
#define DD    256
#define HW    784
#define O1    32

// ws layout (floats):
// [0, 16384)             : sx  [64][256]   per-batch count-sketch of the attr embedding
// [16384, 16384+524288)  : Pt  [64][256][32]  fused sketch2+conv1 matrix, o contiguous

__global__ __launch_bounds__(256) void k1_emb_sketch(
    const float* __restrict__ attr_one_hot,
    const float* __restrict__ W_emb,
    const float* __restrict__ b_emb,
    const int*   __restrict__ h1,
    const float* __restrict__ s1,
    float* __restrict__ sx)
{
    int b = blockIdx.x, t = threadIdx.x;
    __shared__ float s_attr[ATTRN];
    __shared__ float s_sx[DD];
    for (int a = t; a < ATTRN; a += 256) s_attr[a] = attr_one_hot[b * ATTRN + a];
    s_sx[t] = 0.f;
    __syncthreads();
    // emb[b,t] = b_emb[t] + sum_a attr[b,a] * W_emb[t,a]
    float acc = b_emb[t];
    const float* wr = W_emb + t * ATTRN;
#pragma unroll 4
    for (int a = 0; a < ATTRN; ++a) acc += s_attr[a] * wr[a];
    atomicAdd(&s_sx[h1[t]], acc * s1[t]);
    __syncthreads();
    sx[b * DD + t] = s_sx[t];
}

__global__ __launch_bounds__(256) void k2_corr_p(
    const float* __restrict__ sx,
    const float* __restrict__ conv1_w,
    const int*   __restrict__ h2,
    const float* __restrict__ s2,
    float* __restrict__ Pt)
{
    int b = blockIdx.x, og = blockIdx.y, t = threadIdx.x;
    int o0 = og * 8;
    __shared__ float s_sx[DD];
    __shared__ float s_corr[8][DD];
    s_sx[t] = sx[b * DD + t];
    __syncthreads();
    // corr[o,t] = sum_k w1[o,k] * sx[(k - t) & 255]
    float acc[8] = {0.f, 0.f, 0.f, 0.f, 0.f, 0.f, 0.f, 0.f};
    for (int k = 0; k < DD; ++k) {
        float sxv = s_sx[(k - t) & 255];   // per-lane LDS gather, conflict-free rotation
#pragma unroll
        for (int oo = 0; oo < 8; ++oo)
            acc[oo] += conv1_w[(o0 + oo) * CC + k] * sxv;   // uniform idx -> scalar loads
    }
#pragma unroll
    for (int oo = 0; oo < 8; ++oo) s_corr[oo][t] = acc[oo];
    __syncthreads();
    // P_t[b][c][o0+oo] = s2[c] * corr[o0+oo, h2[c]]
    int c = t;
    int h2c = h2[c];
    float s2c = s2[c];
    float* dst = Pt + (b * CC + c) * O1 + o0;
#pragma unroll
    for (int oo = 0; oo < 8; ++oo) dst[oo] = s2c * s_corr[oo][h2c];
}

__global__ __launch_bounds__(256) void k3_main(
    const float* __restrict__ ent,
    const float* __restrict__ Pt,
    const float* __restrict__ conv2_w,
    float* __restrict__ out_map,
    float* __restrict__ out_feat)
{
    int b = blockIdx.x, tile = blockIdx.y, t = threadIdx.x;
    int loc = tile * 256 + t;
    bool valid = loc < HW;
    int locc = valid ? loc : (HW - 1);
    const float* ent_b = ent + (size_t)b * CC * HW;
    const float* Pb = Pt + b * CC * O1;
    float acc[O1];
#pragma unroll
    for (int o = 0; o < O1; ++o) acc[o] = 0.f;
#pragma unroll 2
    for (int c = 0; c < CC; ++c) {
        float e = ent_b[c * HW + locc];          // coalesced across lanes
        const float* prow = Pb + c * O1;         // uniform -> scalar dwordx4 loads
#pragma unroll
        for (int o = 0; o < O1; ++o) acc[o] += prow[o] * e;
    }
    float pre = 0.f;
#pragma unroll
    for (int o = 0; o < O1; ++o) pre += conv2_w[o] * fmaxf(acc[o], 0.f);
    float amap = 1.f / (1.f + expf(-pre));
    if (valid) {
        out_map[b * HW + loc] = amap;
        for (int c = 0; c < CC; ++c) {
            float e = ent_b[c * HW + loc];        // re-read, L2/L3-hot
            out_feat[((size_t)b * CC + c) * HW + loc] = amap * e;
        }
    }
}

extern "C" void kernel_launch(void* const* d_in, const int* in_sizes, int n_in,
                              void* d_out, int out_size, void* d_ws, size_t ws_size,
                              hipStream_t stream) {
    const float* ent   = (const float*)d_in[0];
    const float* attr  = (const float*)d_in[1];
    const float* W_emb = (const float*)d_in[2];
    const float* b_emb = (const float*)d_in[3];
    const int*   h1    = (const int*)d_in[4];
    const float* s1    = (const float*)d_in[5];
    const int*   h2    = (const int*)d_in[6];
    const float* s2    = (const float*)d_in[7];
    const float* c1w   = (const float*)d_in[8];
    const float* c2w   = (const float*)d_in[9];

    float* ws = (float*)d_ws;
    float* sx = ws;
    float* Pt = ws + 16384;

    float* out      = (float*)d_out;
    float* out_map  = out;                 // [64,1,28,28]
    float* out_feat = out + BATCH * HW;    // [64,256,28,28]

    hipLaunchKernelGGL(k1_emb_sketch, dim3(BATCH), dim3(256), 0, stream,
                       attr, W_emb, b_emb, h1, s1, sx);
    hipLaunchKernelGGL(k2_corr_p, dim3(BATCH, 4), dim3(256), 0, stream,
                       sx, c1w, h2, s2, Pt);
    hipLaunchKernelGGL(k3_main, dim3(BATCH, 4), dim3(256), 0, stream,
                       ent, Pt, c2w, out_map, out_feat);
}

// Round 3
// 241.123 us; speedup vs baseline: 1.0008x; 1.0008x over previous
//
#include <hip/hip_runtime.h>
#include <math.h>

#define BATCH 64
#define CC    256
#define ATTRN 300
#define DD    256
#define HW    784
#define O1    32
#define NTILE 13   // ceil(784/64)

// ws layout (floats):
// [0, 16384)             : sx  [64][256]
// [16384, 16384+524288)  : Pt  [64][256][32]  (o contiguous)

// ---------------------------------------------------------------- k1
// emb[b,t] = b_emb[t] + sum_a attr[b,a]*W_emb[t,a];  sx[b][h1[t]] += emb*s1[t]
// W_emb staged through LDS in 32-column chunks so global reads are coalesced.
__global__ __launch_bounds__(256) void k1_emb_sketch(
    const float* __restrict__ attr_one_hot,
    const float* __restrict__ W_emb,
    const float* __restrict__ b_emb,
    const int*   __restrict__ h1,
    const float* __restrict__ s1,
    float* __restrict__ sx)
{
    const int b = blockIdx.x, t = threadIdx.x;
    __shared__ float s_attr[ATTRN];
    __shared__ float s_W[256 * 36];   // pitch 36: 16B-aligned rows, conflict-free b128
    __shared__ float s_sx[DD];

    s_attr[t] = attr_one_hot[b * ATTRN + t];            // t < 256 < 300
    if (t < ATTRN - 256) s_attr[256 + t] = attr_one_hot[b * ATTRN + 256 + t];
    s_sx[t] = 0.f;

    float acc = b_emb[t];
    for (int a0 = 0; a0 < ATTRN; a0 += 32) {
        __syncthreads();
        const int ncol = (ATTRN - a0) < 32 ? (ATTRN - a0) : 32;   // 32 or 12
        const int nf4 = ncol >> 2;                                 // 8 or 3
        for (int i = t; i < 256 * nf4; i += 256) {
            int r = i / nf4, v = i - r * nf4;
            float4 w = *(const float4*)(W_emb + r * ATTRN + a0 + 4 * v);
            *(float4*)(&s_W[r * 36 + 4 * v]) = w;
        }
        __syncthreads();
        for (int v = 0; v < nf4; ++v) {
            float4 wv = *(const float4*)(&s_W[t * 36 + 4 * v]);
            acc += s_attr[a0 + 4 * v]     * wv.x;
            acc += s_attr[a0 + 4 * v + 1] * wv.y;
            acc += s_attr[a0 + 4 * v + 2] * wv.z;
            acc += s_attr[a0 + 4 * v + 3] * wv.w;
        }
    }
    __syncthreads();
    atomicAdd(&s_sx[h1[t]], acc * s1[t]);
    __syncthreads();
    sx[b * DD + t] = s_sx[t];
}

// ---------------------------------------------------------------- k2
// corr[o,t] = sum_k w1[o,k]*sx[(k-t)&255];  Pt[b][c][o] = s2[c]*corr[o,h2[c]]
__global__ __launch_bounds__(256) void k2_corr_p(
    const float* __restrict__ sx,
    const float* __restrict__ conv1_w,
    const int*   __restrict__ h2,
    const float* __restrict__ s2,
    float* __restrict__ Pt)
{
    int b = blockIdx.x, og = blockIdx.y, t = threadIdx.x;
    int o0 = og * 8;
    __shared__ float s_sx[DD];
    __shared__ float s_corr[8][DD];
    s_sx[t] = sx[b * DD + t];
    __syncthreads();
    float acc[8] = {0.f, 0.f, 0.f, 0.f, 0.f, 0.f, 0.f, 0.f};
    for (int k = 0; k < DD; ++k) {
        float sxv = s_sx[(k - t) & 255];
#pragma unroll
        for (int oo = 0; oo < 8; ++oo)
            acc[oo] += conv1_w[(o0 + oo) * CC + k] * sxv;
    }
#pragma unroll
    for (int oo = 0; oo < 8; ++oo) s_corr[oo][t] = acc[oo];
    __syncthreads();
    int c = t;
    int h2c = h2[c];
    float s2c = s2[c];
    float* dst = Pt + (b * CC + c) * O1 + o0;
#pragma unroll
    for (int oo = 0; oo < 8; ++oo) dst[oo] = s2c * s_corr[oo][h2c];
}

// ---------------------------------------------------------------- k3
// Per (b, 64-loc tile): 4 waves each accumulate a 64-channel chunk of
// hidden[32] per location (float4 regs, asm barrier pins the structure),
// LDS reduce -> relu -> conv2 -> sigmoid -> amap; then fused coalesced
// output pass out_feat = amap * ent (L1/L2-hot re-read).
__global__ __launch_bounds__(256) void k3_main(
    const float* __restrict__ ent,
    const float* __restrict__ Pt,
    const float* __restrict__ conv2_w,
    float* __restrict__ out_map,
    float* __restrict__ out_feat)
{
    const int b = blockIdx.x, tile = blockIdx.y;
    const int tid = threadIdx.x;
    const int cg = tid >> 6, l = tid & 63;
    const int loc = tile * 64 + l;
    const bool valid = loc < HW;
    const int locc = valid ? loc : (HW - 1);

    __shared__ float s_part[4][64][33];   // o-pitch 33: conflict-free b32
    __shared__ float s_red[4][64];
    __shared__ float s_amap[64];

    const float* ent_b = ent + (size_t)b * CC * HW;
    const float* Pb = Pt + b * CC * O1;
    const int cbase = cg * 64;

    float4 a0 = make_float4(0.f,0.f,0.f,0.f), a1 = a0, a2 = a0, a3 = a0;
    float4 a4 = a0, a5 = a0, a6 = a0, a7 = a0;

#pragma unroll 4
    for (int cc = 0; cc < 64; ++cc) {
        int c = cbase + cc;
        float e = ent_b[c * HW + locc];
        asm volatile("" : "+v"(e));          // pin: no loop distribution/interchange
        const float4* pr = (const float4*)(Pb + c * O1);   // uniform -> s_load_dwordx4
        float4 p0 = pr[0], p1 = pr[1], p2 = pr[2], p3 = pr[3];
        float4 p4 = pr[4], p5 = pr[5], p6 = pr[6], p7 = pr[7];
        a0.x += p0.x*e; a0.y += p0.y*e; a0.z += p0.z*e; a0.w += p0.w*e;
        a1.x += p1.x*e; a1.y += p1.y*e; a1.z += p1.z*e; a1.w += p1.w*e;
        a2.x += p2.x*e; a2.y += p2.y*e; a2.z += p2.z*e; a2.w += p2.w*e;
        a3.x += p3.x*e; a3.y += p3.y*e; a3.z += p3.z*e; a3.w += p3.w*e;
        a4.x += p4.x*e; a4.y += p4.y*e; a4.z += p4.z*e; a4.w += p4.w*e;
        a5.x += p5.x*e; a5.y += p5.y*e; a5.z += p5.z*e; a5.w += p5.w*e;
        a6.x += p6.x*e; a6.y += p6.y*e; a6.z += p6.z*e; a6.w += p6.w*e;
        a7.x += p7.x*e; a7.y += p7.y*e; a7.z += p7.z*e; a7.w += p7.w*e;
    }

    {
        float* sp = &s_part[cg][l][0];
        sp[0]=a0.x;  sp[1]=a0.y;  sp[2]=a0.z;  sp[3]=a0.w;
        sp[4]=a1.x;  sp[5]=a1.y;  sp[6]=a1.z;  sp[7]=a1.w;
        sp[8]=a2.x;  sp[9]=a2.y;  sp[10]=a2.z; sp[11]=a2.w;
        sp[12]=a3.x; sp[13]=a3.y; sp[14]=a3.z; sp[15]=a3.w;
        sp[16]=a4.x; sp[17]=a4.y; sp[18]=a4.z; sp[19]=a4.w;
        sp[20]=a5.x; sp[21]=a5.y; sp[22]=a5.z; sp[23]=a5.w;
        sp[24]=a6.x; sp[25]=a6.y; sp[26]=a6.z; sp[27]=a6.w;
        sp[28]=a7.x; sp[29]=a7.y; sp[30]=a7.z; sp[31]=a7.w;
    }
    __syncthreads();

    {
        const int oc = cg;
        float partial = 0.f;
#pragma unroll
        for (int j = 0; j < 8; ++j) {
            int o = oc * 8 + j;
            float v = s_part[0][l][o] + s_part[1][l][o]
                    + s_part[2][l][o] + s_part[3][l][o];
            partial += conv2_w[o] * fmaxf(v, 0.f);
        }
        s_red[oc][l] = partial;
    }
    __syncthreads();

    if (tid < 64) {
        float pre = s_red[0][tid] + s_red[1][tid] + s_red[2][tid] + s_red[3][tid];
        float amap = 1.f / (1.f + expf(-pre));
        s_amap[tid] = amap;
        int lc = tile * 64 + tid;
        if (lc < HW) out_map[b * HW + lc] = amap;
    }
    __syncthreads();

    if (valid) {
        const float am = s_amap[l];
#pragma unroll 4
        for (int cc = 0; cc < 64; ++cc) {
            int c = cbase + cc;
            float e = ent_b[c * HW + loc];     // L1/L2-hot re-read
            out_feat[((size_t)b * CC + c) * HW + loc] = am * e;
        }
    }
}

extern "C" void kernel_launch(void* const* d_in, const int* in_sizes, int n_in,
                              void* d_out, int out_size, void* d_ws, size_t ws_size,
                              hipStream_t stream) {
    const float* ent   = (const float*)d_in[0];
    const float* attr  = (const float*)d_in[1];
    const float* W_emb = (const float*)d_in[2];
    const float* b_emb = (const float*)d_in[3];
    const int*   h1    = (const int*)d_in[4];
    const float* s1    = (const float*)d_in[5];
    const int*   h2    = (const int*)d_in[6];
    const float* s2    = (const float*)d_in[7];
    const float* c1w   = (const float*)d_in[8];
    const float* c2w   = (const float*)d_in[9];

    float* ws = (float*)d_ws;
    float* sx = ws;
    float* Pt = ws + 16384;

    float* out      = (float*)d_out;
    float* out_map  = out;                 // [64,1,28,28]
    float* out_feat = out + BATCH * HW;    // [64,256,28,28]

    hipLaunchKernelGGL(k1_emb_sketch, dim3(BATCH), dim3(256), 0, stream,
                       attr, W_emb, b_emb, h1, s1, sx);
    hipLaunchKernelGGL(k2_corr_p, dim3(BATCH, 4), dim3(256), 0, stream,
                       sx, c1w, h2, s2, Pt);
    hipLaunchKernelGGL(k3_main, dim3(BATCH, NTILE), dim3(256), 0, stream,
                       ent, Pt, c2w, out_map, out_feat);
}